// Round 3
// baseline (75.571 us; speedup 1.0000x reference)
//
#include <hip/hip_runtime.h>

// out[c][b] = sum_m in[b][c][m] * W[c][m]
// in : [BATCH, NCLS, NMOD] f32  (NMOD=4 contiguous -> f32x4 per (b,c))
// W  : [NCLS, NMOD] f32
// out: [NCLS, BATCH, 1] f32 -> flat c*BATCH + b

#define BATCH   32768
#define NCLS    400
#define NMOD    4
#define BT      32          // batch rows per block
#define PAD     1
#define LDS_STRIDE (BT + PAD)
#define THREADS 256

typedef float f32x4 __attribute__((ext_vector_type(4)));

__global__ __launch_bounds__(THREADS) void fusion_class_layer_kernel(
    const float* __restrict__ in,   // [B, C, 4]
    const float* __restrict__ W,    // [C, 4]
    float* __restrict__ out)        // [C, B]
{
    __shared__ float lds[NCLS * LDS_STRIDE];   // 52.8 KB -> 3 blocks/CU

    const int b0  = blockIdx.x * BT;
    const int tid = threadIdx.x;

    // Phase 1: coalesced 16B loads (c fastest), dot with W[c], transpose into LDS.
    // BT*NCLS = 12800 elements, 50 iterations of 256 threads.
    for (int idx = tid; idx < BT * NCLS; idx += THREADS) {
        const int b_local = idx / NCLS;
        const int c       = idx - b_local * NCLS;
        const f32x4 v = __builtin_nontemporal_load(
            reinterpret_cast<const f32x4*>(in + ((b0 + b_local) * NCLS + c) * NMOD));
        const f32x4 w = *reinterpret_cast<const f32x4*>(W + c * NMOD);
        lds[c * LDS_STRIDE + b_local] =
            v.x * w.x + v.y * w.y + v.z * w.z + v.w * w.w;
    }

    __syncthreads();

    // Phase 2: vectorized coalesced writes. 8 f32x4 per class row, 3200 total.
    for (int idx = tid; idx < (BT * NCLS) / 4; idx += THREADS) {
        const int c  = idx >> 3;        // idx / 8
        const int bl = (idx & 7) * 4;   // f32x4 slot within the 32-wide row
        const float* l = &lds[c * LDS_STRIDE + bl];
        f32x4 o;
        o.x = l[0]; o.y = l[1]; o.z = l[2]; o.w = l[3];
        __builtin_nontemporal_store(
            o, reinterpret_cast<f32x4*>(out + c * BATCH + b0 + bl));
    }
}

extern "C" void kernel_launch(void* const* d_in, const int* in_sizes, int n_in,
                              void* d_out, int out_size, void* d_ws, size_t ws_size,
                              hipStream_t stream) {
    const float* in  = (const float*)d_in[0];   // logit_concat [32768,400,4]
    const float* W   = (const float*)d_in[1];   // [400,4]
    float*       out = (float*)d_out;           // [400,32768,1]

    const int grid = BATCH / BT;                // 1024 blocks
    fusion_class_layer_kernel<<<grid, THREADS, 0, stream>>>(in, W, out);
}

// Round 4
// 49.623 us; speedup vs baseline: 1.5229x; 1.5229x over previous
//
#include <hip/hip_runtime.h>

// out[c][b] = sum_m in[b][c][m] * W[c][m]
// in : [BATCH, NCLS, NMOD] f32  (NMOD=4 contiguous -> f32x4 per (b,c))
// W  : [NCLS, NMOD] f32
// out: [NCLS, BATCH, 1] f32 -> flat c*BATCH + b

#define BATCH   32768
#define NCLS    400
#define NMOD    4
#define BT      32          // batch rows per block
#define PAD     1
#define LDS_STRIDE (BT + PAD)
#define THREADS 256

typedef float f32x4 __attribute__((ext_vector_type(4)));

__global__ __launch_bounds__(THREADS) void fusion_class_layer_kernel(
    const float* __restrict__ in,   // [B, C, 4]
    const float* __restrict__ W,    // [C, 4]
    float* __restrict__ out)        // [C, B]
{
    __shared__ float lds[NCLS * LDS_STRIDE];   // 52.8 KB -> 3 blocks/CU

    const int b0  = blockIdx.x * BT;
    const int tid = threadIdx.x;

    // Phase 1: coalesced 16B loads (c fastest), dot with W[c], transpose into LDS.
    // BT*NCLS = 12800 elements, 50 iterations of 256 threads.
    for (int idx = tid; idx < BT * NCLS; idx += THREADS) {
        const int b_local = idx / NCLS;
        const int c       = idx - b_local * NCLS;
        const f32x4 v = *reinterpret_cast<const f32x4*>(
            in + ((b0 + b_local) * NCLS + c) * NMOD);
        const f32x4 w = *reinterpret_cast<const f32x4*>(W + c * NMOD);
        lds[c * LDS_STRIDE + b_local] =
            v.x * w.x + v.y * w.y + v.z * w.z + v.w * w.w;
    }

    __syncthreads();

    // Phase 2: vectorized coalesced writes. 8 f32x4 per class row, 3200 total.
    for (int idx = tid; idx < (BT * NCLS) / 4; idx += THREADS) {
        const int c  = idx >> 3;        // idx / 8
        const int bl = (idx & 7) * 4;   // f32x4 slot within the 32-wide row
        const float* l = &lds[c * LDS_STRIDE + bl];
        f32x4 o;
        o.x = l[0]; o.y = l[1]; o.z = l[2]; o.w = l[3];
        *reinterpret_cast<f32x4*>(out + c * BATCH + b0 + bl) = o;
    }
}

extern "C" void kernel_launch(void* const* d_in, const int* in_sizes, int n_in,
                              void* d_out, int out_size, void* d_ws, size_t ws_size,
                              hipStream_t stream) {
    const float* in  = (const float*)d_in[0];   // logit_concat [32768,400,4]
    const float* W   = (const float*)d_in[1];   // [400,4]
    float*       out = (float*)d_out;           // [400,32768,1]

    const int grid = BATCH / BT;                // 1024 blocks
    fusion_class_layer_kernel<<<grid, THREADS, 0, stream>>>(in, W, out);
}

// Round 5
// 43.422 us; speedup vs baseline: 1.7404x; 1.1428x over previous
//
#include <hip/hip_runtime.h>

// out[c][b] = sum_m in[b][c][m] * W[c][m]
// in : [BATCH, NCLS, NMOD] f32  (NMOD=4 contiguous -> f32x4 per (b,c))
// W  : [NCLS, NMOD] f32
// out: [NCLS, BATCH, 1] f32 -> flat c*BATCH + b

#define BATCH   32768
#define NCLS    400
#define CCHUNK  200         // classes per sequential chunk (2 chunks)
#define NMOD    4
#define BT      32          // batch rows per block
#define PAD     1
#define LDS_STRIDE (BT + PAD)
#define THREADS 256

typedef float f32x4 __attribute__((ext_vector_type(4)));

__global__ __launch_bounds__(THREADS) void fusion_class_layer_kernel(
    const float* __restrict__ in,   // [B, C, 4]
    const float* __restrict__ W,    // [C, 4]
    float* __restrict__ out)        // [C, B]
{
    // 200*33*4 = 26.4 KB -> 6 blocks/CU capacity; grid 1024 = 4/CU fully resident.
    __shared__ float lds[CCHUNK * LDS_STRIDE];

    const int b0  = blockIdx.x * BT;
    const int tid = threadIdx.x;

    for (int c0 = 0; c0 < NCLS; c0 += CCHUNK) {
        // Phase 1: coalesced 16B loads (c fastest), dot with W[c], transpose into LDS.
        // BT*CCHUNK = 6400 elements, 25 iterations of 256 threads.
        for (int idx = tid; idx < BT * CCHUNK; idx += THREADS) {
            const int b_local = idx / CCHUNK;
            const int c       = idx - b_local * CCHUNK;   // class within chunk
            const f32x4 v = *reinterpret_cast<const f32x4*>(
                in + ((b0 + b_local) * NCLS + c0 + c) * NMOD);
            const f32x4 w = *reinterpret_cast<const f32x4*>(W + (c0 + c) * NMOD);
            lds[c * LDS_STRIDE + b_local] =
                v.x * w.x + v.y * w.y + v.z * w.z + v.w * w.w;
        }

        __syncthreads();

        // Phase 2: coalesced scalar writes (b fastest within each class row).
        for (int idx = tid; idx < BT * CCHUNK; idx += THREADS) {
            const int c       = idx >> 5;          // idx / BT (BT=32)
            const int b_local = idx & (BT - 1);    // idx % BT
            out[(c0 + c) * BATCH + b0 + b_local] = lds[c * LDS_STRIDE + b_local];
        }

        __syncthreads();   // protect LDS reuse across chunks
    }
}

extern "C" void kernel_launch(void* const* d_in, const int* in_sizes, int n_in,
                              void* d_out, int out_size, void* d_ws, size_t ws_size,
                              hipStream_t stream) {
    const float* in  = (const float*)d_in[0];   // logit_concat [32768,400,4]
    const float* W   = (const float*)d_in[1];   // [400,4]
    float*       out = (float*)d_out;           // [400,32768,1]

    const int grid = BATCH / BT;                // 1024 blocks, all co-resident
    fusion_class_layer_kernel<<<grid, THREADS, 0, stream>>>(in, W, out);
}